// Round 6
// baseline (42.806 us; speedup 1.0000x reference)
//
#include <hip/hip_runtime.h>
#include <float.h>

// Problem constants (fixed shapes from the reference).
#define BB 8
#define QQ 100
#define CC 19
#define MHH 128
#define MWW 128
#define IMG_ 512

// Round-6: exact round-2 structure (BANDS=8 -> 1216 blocks, all co-resident
// at 4.75/CU; best measured 37.5us) + ONE isolated change: non-temporal
// stores for the 159 MB write-once output (skip L2 allocation, keep L2 for
// mask halo + cls reuse).  Mask loads stay normal (halo wants L2 hits).
// History: BANDS=4 regressed (CU quantization, 48.5us); BANDS=16 regressed
// (extra halo + per-block overhead, 38.2us).
#define BANDS 8
#define BROWS (MHH / BANDS)      // 16 source rows per band
#define SROWS (BROWS + 2)        // +1 halo row each side = 18
#define OROWS (IMG_ / BANDS)     // 64 output rows per band
#define NTHREADS 256

// clang-native 4-float vector: required by __builtin_nontemporal_store
// (HIP's float4 is a class type, rejected by the builtin).
typedef float f32x4 __attribute__((ext_vector_type(4)));

// ---------------------------------------------------------------------------
// One fused kernel: argmax -> grouped segment-max (into LDS) -> bilinear 4x
// upsample, per (b,c,band) block.  No intermediate HBM buffer.
//
// Bilinear weights (half-pixel, scale 4) are compile-time constants:
//   out index 4j+p samples src j-1/j (p=0,1) or j/j+1 (p=2,3) with weights
//   p=0: .375/.625   p=1: .125/.875   p=2: .875/.125   p=3: .625/.375
// Border handling via index clamp == jax's renormalized 2-tap triangle kernel
// (validated: absmax 1.6e-2 within threshold).
// ---------------------------------------------------------------------------
__global__ __launch_bounds__(NTHREADS)
void fused_kernel(const float* __restrict__ cls,
                  const float* __restrict__ masks,
                  float* __restrict__ out) {
    const int bc   = blockIdx.x;           // b*C + c
    const int band = blockIdx.y;           // 0..BANDS-1
    const int b = bc / CC;
    const int c = bc % CC;
    const int tid = threadIdx.x;

    __shared__ int   s_pred[QQ];
    __shared__ int   s_q[QQ];
    __shared__ int   s_n;
    __shared__ float s_tile[SROWS][MWW];   // 18*128*4 = 9216 B

    if (tid == 0) s_n = 0;
    // --- stage 1: per-query argmax over real classes (cls is 64 KB total,
    //     L2/L3-resident across the 1216 blocks) ---
    if (tid < QQ) {
        const float* p = cls + (size_t)(b * QQ + tid) * (CC + 1);
        float best = p[0];
        int bi = 0;
#pragma unroll
        for (int k = 1; k < CC; ++k) {
            float v = p[k];
            if (v > best) { best = v; bi = k; }   // first-max, matches jnp.argmax
        }
        s_pred[tid] = bi;
    }
    __syncthreads();
    if (tid < QQ && s_pred[tid] == c) {
        int slot = atomicAdd(&s_n, 1);
        s_q[slot] = tid;
    }
    __syncthreads();
    const int nq = s_n;

    // --- stage 2: segment-max the 18 (clamped) source rows into LDS ---
    const int r0 = band * BROWS - 1;       // global row of LDS row 0 (unclamped)
    float4* tile4 = (float4*)&s_tile[0][0];
    const int NSLOT = SROWS * (MWW / 4);   // 576 float4 slots
    for (int s = tid; s < NSLOT; s += NTHREADS) {
        const int lr = s >> 5;             // 32 float4 per row
        const int cg = s & 31;
        const int g  = min(max(r0 + lr, 0), MHH - 1);
        float4 m = make_float4(0.f, 0.f, 0.f, 0.f);
        if (nq > 0) {
            m = make_float4(-FLT_MAX, -FLT_MAX, -FLT_MAX, -FLT_MAX);
            for (int t = 0; t < nq; ++t) {
                const float4* mp = (const float4*)(
                    masks + (((size_t)(b * QQ + s_q[t])) * MHH + g) * MWW);
                float4 v = mp[cg];
                m.x = fmaxf(m.x, v.x);
                m.y = fmaxf(m.y, v.y);
                m.z = fmaxf(m.z, v.z);
                m.w = fmaxf(m.w, v.w);
            }
        }
        tile4[s] = m;
    }
    __syncthreads();

    // --- stage 3: bilinear 4x upsample, 4 output rows per item ---
    // items: 16 row-groups (j) x 128 x-groups, each emits 4 aligned float4.
    for (int i = tid; i < (BROWS) * (MWW); i += NTHREADS) {   // 16*128 = 2048
        const int jj = i >> 7;             // row group within band (0..15)
        const int xg = i & 127;            // float4 column group (0..127)
        const int km = max(xg - 1, 0);
        const int kp = min(xg + 1, MWW - 1);

        // three source rows: global j-1, j, j+1 -> LDS rows jj, jj+1, jj+2
        const float am = s_tile[jj][km],     a0 = s_tile[jj][xg],     ap = s_tile[jj][kp];
        const float bm = s_tile[jj + 1][km], b0 = s_tile[jj + 1][xg], bp = s_tile[jj + 1][kp];
        const float cm = s_tile[jj + 2][km], c0 = s_tile[jj + 2][xg], cp = s_tile[jj + 2][kp];

        float* orow = out + ((size_t)bc * IMG_ + (size_t)band * OROWS + jj * 4) * IMG_;

        f32x4 o;
        // p = 0: .375*row(j-1) + .625*row(j)
        {
            const float vm = am * 0.375f + bm * 0.625f;
            const float v0 = a0 * 0.375f + b0 * 0.625f;
            const float vp = ap * 0.375f + bp * 0.625f;
            o.x = vm * 0.375f + v0 * 0.625f;
            o.y = vm * 0.125f + v0 * 0.875f;
            o.z = v0 * 0.875f + vp * 0.125f;
            o.w = v0 * 0.625f + vp * 0.375f;
            __builtin_nontemporal_store(o, &((f32x4*)orow)[xg]);
        }
        // p = 1: .125*row(j-1) + .875*row(j)
        {
            const float vm = am * 0.125f + bm * 0.875f;
            const float v0 = a0 * 0.125f + b0 * 0.875f;
            const float vp = ap * 0.125f + bp * 0.875f;
            o.x = vm * 0.375f + v0 * 0.625f;
            o.y = vm * 0.125f + v0 * 0.875f;
            o.z = v0 * 0.875f + vp * 0.125f;
            o.w = v0 * 0.625f + vp * 0.375f;
            __builtin_nontemporal_store(o, &((f32x4*)(orow + IMG_))[xg]);
        }
        // p = 2: .875*row(j) + .125*row(j+1)
        {
            const float vm = bm * 0.875f + cm * 0.125f;
            const float v0 = b0 * 0.875f + c0 * 0.125f;
            const float vp = bp * 0.875f + cp * 0.125f;
            o.x = vm * 0.375f + v0 * 0.625f;
            o.y = vm * 0.125f + v0 * 0.875f;
            o.z = v0 * 0.875f + vp * 0.125f;
            o.w = v0 * 0.625f + vp * 0.375f;
            __builtin_nontemporal_store(o, &((f32x4*)(orow + 2 * IMG_))[xg]);
        }
        // p = 3: .625*row(j) + .375*row(j+1)
        {
            const float vm = bm * 0.625f + cm * 0.375f;
            const float v0 = b0 * 0.625f + c0 * 0.375f;
            const float vp = bp * 0.625f + cp * 0.375f;
            o.x = vm * 0.375f + v0 * 0.625f;
            o.y = vm * 0.125f + v0 * 0.875f;
            o.z = v0 * 0.875f + vp * 0.125f;
            o.w = v0 * 0.625f + vp * 0.375f;
            __builtin_nontemporal_store(o, &((f32x4*)(orow + 3 * IMG_))[xg]);
        }
    }
}

// ---------------------------------------------------------------------------
extern "C" void kernel_launch(void* const* d_in, const int* in_sizes, int n_in,
                              void* d_out, int out_size, void* d_ws, size_t ws_size,
                              hipStream_t stream) {
    const float* cls   = (const float*)d_in[0];  // [B, Q, C+1] f32
    const float* masks = (const float*)d_in[1];  // [B, Q, 128, 128] f32
    float* out = (float*)d_out;                  // [B, C, 512, 512] f32

    dim3 grid(BB * CC, BANDS);                   // 152 x 8 = 1216 blocks
    fused_kernel<<<grid, NTHREADS, 0, stream>>>(cls, masks, out);
}

// Round 7
// 38.162 us; speedup vs baseline: 1.1217x; 1.1217x over previous
//
#include <hip/hip_runtime.h>
#include <float.h>

// Problem constants (fixed shapes from the reference).
#define BB 8
#define QQ 100
#define CC 19
#define MHH 128
#define MWW 128
#define IMG_ 512

// FINAL (round-2 configuration, best measured 37.5us = 5.83 TB/s mixed
// stream = 93% of the 6.29 TB/s copy ceiling).  A/B history:
//   - 3-kernel pipeline:        49.9us  (seg round-trip + launch gaps)
//   - fused, BANDS=8:           37.5us  <- this kernel
//   - BANDS=4:                  48.5us  (608 blocks = 2.375/CU quantization)
//   - BANDS=16:                 38.2us  (+12.5% halo, more per-block preamble)
//   - nontemporal loads+stores: 48.5us  (bundled, regressed)
//   - nontemporal stores alone: 42.8us  (L2 write-coalescing bypassed; NT
//                                        stores are a LOSS for streaming
//                                        writes on gfx950)
#define BANDS 8
#define BROWS (MHH / BANDS)      // 16 source rows per band
#define SROWS (BROWS + 2)        // +1 halo row each side = 18
#define OROWS (IMG_ / BANDS)     // 64 output rows per band
#define NTHREADS 256

// ---------------------------------------------------------------------------
// One fused kernel: argmax -> grouped segment-max (into LDS) -> bilinear 4x
// upsample, per (b,c,band) block.  No intermediate HBM buffer.
//
// Bilinear weights (half-pixel, scale 4) are compile-time constants:
//   out index 4j+p samples src j-1/j (p=0,1) or j/j+1 (p=2,3) with weights
//   p=0: .375/.625   p=1: .125/.875   p=2: .875/.125   p=3: .625/.375
// Border handling via index clamp == jax's renormalized 2-tap triangle kernel
// (validated: absmax 1.6e-2 within threshold).
// ---------------------------------------------------------------------------
__global__ __launch_bounds__(NTHREADS)
void fused_kernel(const float* __restrict__ cls,
                  const float* __restrict__ masks,
                  float* __restrict__ out) {
    const int bc   = blockIdx.x;           // b*C + c
    const int band = blockIdx.y;           // 0..BANDS-1
    const int b = bc / CC;
    const int c = bc % CC;
    const int tid = threadIdx.x;

    __shared__ int   s_pred[QQ];
    __shared__ int   s_q[QQ];
    __shared__ int   s_n;
    __shared__ float s_tile[SROWS][MWW];   // 18*128*4 = 9216 B

    if (tid == 0) s_n = 0;
    // --- stage 1: per-query argmax over real classes (cls is 64 KB total,
    //     L2/L3-resident across the 1216 blocks) ---
    if (tid < QQ) {
        const float* p = cls + (size_t)(b * QQ + tid) * (CC + 1);
        float best = p[0];
        int bi = 0;
#pragma unroll
        for (int k = 1; k < CC; ++k) {
            float v = p[k];
            if (v > best) { best = v; bi = k; }   // first-max, matches jnp.argmax
        }
        s_pred[tid] = bi;
    }
    __syncthreads();
    if (tid < QQ && s_pred[tid] == c) {
        int slot = atomicAdd(&s_n, 1);
        s_q[slot] = tid;
    }
    __syncthreads();
    const int nq = s_n;

    // --- stage 2: segment-max the 18 (clamped) source rows into LDS ---
    const int r0 = band * BROWS - 1;       // global row of LDS row 0 (unclamped)
    float4* tile4 = (float4*)&s_tile[0][0];
    const int NSLOT = SROWS * (MWW / 4);   // 576 float4 slots
    for (int s = tid; s < NSLOT; s += NTHREADS) {
        const int lr = s >> 5;             // 32 float4 per row
        const int cg = s & 31;
        const int g  = min(max(r0 + lr, 0), MHH - 1);
        float4 m = make_float4(0.f, 0.f, 0.f, 0.f);
        if (nq > 0) {
            m = make_float4(-FLT_MAX, -FLT_MAX, -FLT_MAX, -FLT_MAX);
            for (int t = 0; t < nq; ++t) {
                const float4* mp = (const float4*)(
                    masks + (((size_t)(b * QQ + s_q[t])) * MHH + g) * MWW);
                float4 v = mp[cg];
                m.x = fmaxf(m.x, v.x);
                m.y = fmaxf(m.y, v.y);
                m.z = fmaxf(m.z, v.z);
                m.w = fmaxf(m.w, v.w);
            }
        }
        tile4[s] = m;
    }
    __syncthreads();

    // --- stage 3: bilinear 4x upsample, 4 output rows per item ---
    // items: 16 row-groups (j) x 128 x-groups, each emits 4 aligned float4.
    for (int i = tid; i < (BROWS) * (MWW); i += NTHREADS) {   // 16*128 = 2048
        const int jj = i >> 7;             // row group within band (0..15)
        const int xg = i & 127;            // float4 column group (0..127)
        const int km = max(xg - 1, 0);
        const int kp = min(xg + 1, MWW - 1);

        // three source rows: global j-1, j, j+1 -> LDS rows jj, jj+1, jj+2
        const float am = s_tile[jj][km],     a0 = s_tile[jj][xg],     ap = s_tile[jj][kp];
        const float bm = s_tile[jj + 1][km], b0 = s_tile[jj + 1][xg], bp = s_tile[jj + 1][kp];
        const float cm = s_tile[jj + 2][km], c0 = s_tile[jj + 2][xg], cp = s_tile[jj + 2][kp];

        float* orow = out + ((size_t)bc * IMG_ + (size_t)band * OROWS + jj * 4) * IMG_;

        float4 o;
        // p = 0: .375*row(j-1) + .625*row(j)
        {
            const float vm = am * 0.375f + bm * 0.625f;
            const float v0 = a0 * 0.375f + b0 * 0.625f;
            const float vp = ap * 0.375f + bp * 0.625f;
            o.x = vm * 0.375f + v0 * 0.625f;
            o.y = vm * 0.125f + v0 * 0.875f;
            o.z = v0 * 0.875f + vp * 0.125f;
            o.w = v0 * 0.625f + vp * 0.375f;
            ((float4*)orow)[xg] = o;
        }
        // p = 1: .125*row(j-1) + .875*row(j)
        {
            const float vm = am * 0.125f + bm * 0.875f;
            const float v0 = a0 * 0.125f + b0 * 0.875f;
            const float vp = ap * 0.125f + bp * 0.875f;
            o.x = vm * 0.375f + v0 * 0.625f;
            o.y = vm * 0.125f + v0 * 0.875f;
            o.z = v0 * 0.875f + vp * 0.125f;
            o.w = v0 * 0.625f + vp * 0.375f;
            ((float4*)(orow + IMG_))[xg] = o;
        }
        // p = 2: .875*row(j) + .125*row(j+1)
        {
            const float vm = bm * 0.875f + cm * 0.125f;
            const float v0 = b0 * 0.875f + c0 * 0.125f;
            const float vp = bp * 0.875f + cp * 0.125f;
            o.x = vm * 0.375f + v0 * 0.625f;
            o.y = vm * 0.125f + v0 * 0.875f;
            o.z = v0 * 0.875f + vp * 0.125f;
            o.w = v0 * 0.625f + vp * 0.375f;
            ((float4*)(orow + 2 * IMG_))[xg] = o;
        }
        // p = 3: .625*row(j) + .375*row(j+1)
        {
            const float vm = bm * 0.625f + cm * 0.375f;
            const float v0 = b0 * 0.625f + c0 * 0.375f;
            const float vp = bp * 0.625f + cp * 0.375f;
            o.x = vm * 0.375f + v0 * 0.625f;
            o.y = vm * 0.125f + v0 * 0.875f;
            o.z = v0 * 0.875f + vp * 0.125f;
            o.w = v0 * 0.625f + vp * 0.375f;
            ((float4*)(orow + 3 * IMG_))[xg] = o;
        }
    }
}

// ---------------------------------------------------------------------------
extern "C" void kernel_launch(void* const* d_in, const int* in_sizes, int n_in,
                              void* d_out, int out_size, void* d_ws, size_t ws_size,
                              hipStream_t stream) {
    const float* cls   = (const float*)d_in[0];  // [B, Q, C+1] f32
    const float* masks = (const float*)d_in[1];  // [B, Q, 128, 128] f32
    float* out = (float*)d_out;                  // [B, C, 512, 512] f32

    dim3 grid(BB * CC, BANDS);                   // 152 x 8 = 1216 blocks
    fused_kernel<<<grid, NTHREADS, 0, stream>>>(cls, masks, out);
}